// Round 1
// baseline (1153.633 us; speedup 1.0000x reference)
//
#include <hip/hip_runtime.h>

// Fused: 1x1(64->384) -> dw3x3 -> split qkv -> per-8x8-patch circular conv(q,k)
//        -> channel LayerNorm -> v*norm -> 1x1(128->64)
// One workgroup per (batch, 8x8 patch). 512 threads. Dynamic LDS 112128 B.
//
// LDS layout (floats):
//   hs   [64][105]  hidden chunk on 10x10 tile (pad 105 vs bank conflicts)
//   qs   [128][68]  q patch (pad 68 -> 16B-aligned rows for float4 reads)
//   tmp  [64][65]   k/v chunk patch, then gated values (pad 65 conflict-free)
//   cc   [128][65]  circular-conv output
//   mu_s [64], s2_s [64]  LN stats per pixel
#define HS_OFF   0
#define QS_OFF   6720
#define TMP_OFF  15424
#define CC_OFF   19584
#define MU_OFF   27904
#define S2_OFF   27968
#define LDS_FLOATS 28032

__global__ __launch_bounds__(512, 2) void lfsa_fused(
    const float* __restrict__ x,
    const float* __restrict__ wh,
    const float* __restrict__ wdw,
    const float* __restrict__ nw,
    const float* __restrict__ nb,
    const float* __restrict__ wo,
    float* __restrict__ out)
{
    extern __shared__ float lds[];
    float* hs   = lds + HS_OFF;
    float* qs   = lds + QS_OFF;
    float* tmp  = lds + TMP_OFF;
    float* cc   = lds + CC_OFF;
    float* mu_s = lds + MU_OFF;
    float* s2_s = lds + S2_OFF;

    const int tid = threadIdx.x;
    const int px = blockIdx.x, py = blockIdx.y, bz = blockIdx.z;

    // ---- stage x tile (10x10 with zero halo) into registers ----
    // lanes = tile pixels (128-thread groups cover 100 pixels), 4 o-split groups
    const int pix  = tid & 127;
    const int g    = tid >> 7;            // 0..3
    const int prow = pix / 10;
    const int pcol = pix - prow * 10;
    const int yy = py * 8 + prow - 1;
    const int xx = px * 8 + pcol - 1;
    const bool pvalid = (pix < 100);
    const bool inimg  = pvalid && ((unsigned)yy < 256u) && ((unsigned)xx < 256u);
    const float* xp = inimg ? (x + (((size_t)bz * 64) * 256 + (size_t)yy) * 256 + xx) : x;
    float xreg[64];
    #pragma unroll
    for (int c = 0; c < 64; ++c)
        xreg[c] = inimg ? xp[(size_t)c * 65536] : 0.0f;

    // per-phase mappings
    const int dwo  = tid >> 3;            // dw / circ / gate: channel-in-chunk 0..63
    const int blk  = tid & 7;             // dw: 2x4 output block
    const int by2  = (blk >> 1) * 2;
    const int bx4  = (blk & 1) * 4;
    const int ci   = tid & 7;             // circ: output row, gate: col-group
    const int wv   = tid >> 6;            // proj: wave index 0..7
    const int lane = tid & 63;            // proj: pixel

    float pacc[8];
    #pragma unroll
    for (int i = 0; i < 8; ++i) pacc[i] = 0.0f;

    #pragma unroll 1
    for (int kc = 0; kc < 6; ++kc) {
        const int o0 = kc * 64;

        // ---- 1x1 conv GEMM: hidden chunk -> hs (w via scalar loads) ----
        #pragma unroll 1
        for (int oi = 0; oi < 16; oi += 2) {
            const int o_loc = g * 16 + oi;
            const int o_u = __builtin_amdgcn_readfirstlane(o0 + o_loc);
            const float* w0 = wh + o_u * 64;
            float a0 = 0.0f, a1 = 0.0f;
            #pragma unroll
            for (int c = 0; c < 64; ++c) {
                a0 = fmaf(w0[c],      xreg[c], a0);
                a1 = fmaf(w0[64 + c], xreg[c], a1);
            }
            if (pvalid) {
                hs[105 * o_loc + pix]       = a0;
                hs[105 * o_loc + 105 + pix] = a1;
            }
        }
        __syncthreads();

        // ---- depthwise 3x3 (zero pad baked into hs halo) ----
        {
            const int og = o0 + dwo;
            float w9[9];
            #pragma unroll
            for (int t = 0; t < 9; ++t) w9[t] = wdw[og * 9 + t];
            float in[4][6];
            #pragma unroll
            for (int r = 0; r < 4; ++r)
                #pragma unroll
                for (int c = 0; c < 6; ++c)
                    in[r][c] = hs[105 * dwo + (by2 + r) * 10 + (bx4 + c)];
            float* dst = (kc < 2) ? (qs + 68 * (o0 + dwo)) : (tmp + 65 * dwo);
            #pragma unroll
            for (int r = 0; r < 2; ++r) {
                #pragma unroll
                for (int c = 0; c < 4; ++c) {
                    float s = 0.0f;
                    #pragma unroll
                    for (int dy = 0; dy < 3; ++dy)
                        #pragma unroll
                        for (int dx = 0; dx < 3; ++dx)
                            s = fmaf(w9[dy * 3 + dx], in[r + dy][c + dx], s);
                    dst[(by2 + r) * 8 + bx4 + c] = s;
                }
            }
        }
        __syncthreads();

        if (kc == 2 || kc == 3) {
            // ---- circular conv per channel: cc[i][j] = sum_ab q[a][b]*k[(i-a)&7][(j-b)&7]
            const int ch = (kc - 2) * 64 + dwo;
            float q[64];
            #pragma unroll
            for (int t = 0; t < 16; ++t) {
                const float4 v4 = *(const float4*)&qs[68 * ch + 4 * t];
                q[4*t] = v4.x; q[4*t+1] = v4.y; q[4*t+2] = v4.z; q[4*t+3] = v4.w;
            }
            float acc[8];
            #pragma unroll
            for (int j = 0; j < 8; ++j) acc[j] = 0.0f;
            #pragma unroll
            for (int a = 0; a < 8; ++a) {
                const int r = (ci - a) & 7;
                float kr[8];
                #pragma unroll
                for (int j = 0; j < 8; ++j) kr[j] = tmp[65 * dwo + 8 * r + j];
                #pragma unroll
                for (int bb = 0; bb < 8; ++bb) {
                    const float qv = q[a * 8 + bb];
                    #pragma unroll
                    for (int j = 0; j < 8; ++j)
                        acc[j] = fmaf(qv, kr[(j - bb) & 7], acc[j]);
                }
            }
            #pragma unroll
            for (int j = 0; j < 8; ++j) cc[65 * ch + 8 * ci + j] = acc[j];
        }

        if (kc == 3) {
            __syncthreads();
            // ---- LayerNorm stats over 128 channels per pixel (waves 0 & 1) ----
            if (tid < 64) {
                float s = 0.0f;
                #pragma unroll
                for (int chh = 0; chh < 128; ++chh) s += cc[65 * chh + tid];
                mu_s[tid] = s * (1.0f / 128.0f);
            } else if (tid < 128) {
                const int p = tid - 64;
                float s = 0.0f;
                #pragma unroll
                for (int chh = 0; chh < 128; ++chh) {
                    const float v = cc[65 * chh + p];
                    s = fmaf(v, v, s);
                }
                s2_s[p] = s * (1.0f / 128.0f);
            }
        }

        if (kc >= 4) {
            // ---- gate: tmp <- v * ((cc - mu) * rstd * nw + nb), in place ----
            const int ch2 = (kc - 4) * 64 + dwo;
            const float nwv = nw[ch2], nbv = nb[ch2];
            const int pq = ci * 8;
            #pragma unroll
            for (int j = 0; j < 8; ++j) {
                const int p = pq + j;
                const float v   = tmp[65 * dwo + p];
                const float c0  = cc[65 * ch2 + p];
                const float m   = mu_s[p];
                const float var = s2_s[p] - m * m;
                const float rstd = rsqrtf(var + 1e-5f);
                tmp[65 * dwo + p] = v * ((c0 - m) * rstd * nwv + nbv);
            }
            __syncthreads();
            // ---- projection accumulate (w_out via scalar loads) ----
            const int obase = __builtin_amdgcn_readfirstlane(wv * 8);
            const int cb = (kc - 4) * 64;
            #pragma unroll 4
            for (int c = 0; c < 64; ++c) {
                const float gv = tmp[65 * c + lane];
                const float* wrow = wo + cb + c;
                #pragma unroll
                for (int ow = 0; ow < 8; ++ow)
                    pacc[ow] = fmaf(wrow[(obase + ow) * 128], gv, pacc[ow]);
            }
        }
        __syncthreads();
    }

    // ---- write output patch: 8 waves x 8 o-channels, lanes = 64 pixels ----
    {
        const int r = lane >> 3, c8 = lane & 7;
        const size_t oy = (size_t)py * 8 + r;
        const size_t ox = (size_t)px * 8 + c8;
        #pragma unroll
        for (int ow = 0; ow < 8; ++ow) {
            const int o = wv * 8 + ow;
            out[(((size_t)bz * 64 + o) * 256 + oy) * 256 + ox] = pacc[ow];
        }
    }
}

extern "C" void kernel_launch(void* const* d_in, const int* in_sizes, int n_in,
                              void* d_out, int out_size, void* d_ws, size_t ws_size,
                              hipStream_t stream) {
    const float* x   = (const float*)d_in[0];
    const float* wh  = (const float*)d_in[1];
    const float* wdw = (const float*)d_in[2];
    const float* nw  = (const float*)d_in[3];
    const float* nb  = (const float*)d_in[4];
    const float* wo  = (const float*)d_in[5];
    float* outp = (float*)d_out;
    // d_in[6] = patch_size (always 8 per setup_inputs); unused on device.

    const int lds_bytes = LDS_FLOATS * 4;  // 112128 B, needs opt-in above 64 KB
    (void)hipFuncSetAttribute((const void*)lfsa_fused,
                              hipFuncAttributeMaxDynamicSharedMemorySize, lds_bytes);
    dim3 grid(32, 32, 4);
    lfsa_fused<<<grid, 512, lds_bytes, stream>>>(x, wh, wdw, nw, nb, wo, outp);
}

// Round 2
// 540.779 us; speedup vs baseline: 2.1333x; 2.1333x over previous
//
#include <hip/hip_runtime.h>

// Fused: 1x1(64->384, MFMA fp16) -> dw3x3 (fp32 VALU) -> per-8x8-patch circular
//        conv(q,k) (fp32 VALU) -> channel LayerNorm -> v*norm -> 1x1(128->64, MFMA fp16)
// One workgroup per (batch, 8x8 patch). 512 threads. Dynamic LDS 132480 B.

typedef _Float16 f16x8 __attribute__((ext_vector_type(8)));
typedef _Float16 f16x4 __attribute__((ext_vector_type(4)));
typedef float    f32x4 __attribute__((ext_vector_type(4)));

// LDS layout (float offsets)
#define XS_OFF   0      // f16 [112][68] x tile (10x10 + zero halo + pad rows 100..111)
#define HS_OFF   3808   // f32 [64][105] hidden chunk on 10x10 tile
#define QS_OFF   10528  // f32 [128][68] q patch;  gs f16 [64][136] aliases (kc>=4)
#define TMP_OFF  19232  // f32 [64][65]  k/v chunk patch
#define CC_OFF   23392  // f32 [128][65] circular-conv output
#define MUP_OFF  31712  // f32 [8][64] partial mean
#define S2P_OFF  32224  // f32 [8][64] partial sumsq
#define MU_OFF   32736  // f32 [64]
#define S2_OFF   32800  // f32 [64]
#define LNW_OFF  32864  // f32 [128]
#define LNB_OFF  32992  // f32 [128]
#define LDS_FLOATS 33120

__global__ __launch_bounds__(512, 2) void lfsa_fused(
    const float* __restrict__ x,
    const float* __restrict__ wh,
    const float* __restrict__ wdw,
    const float* __restrict__ nw,
    const float* __restrict__ nb,
    const float* __restrict__ wo,
    float* __restrict__ out)
{
    extern __shared__ float lds[];
    _Float16* xs = (_Float16*)lds;             // [112][68]
    float* hs   = lds + HS_OFF;
    float* qs   = lds + QS_OFF;
    _Float16* gs = (_Float16*)(lds + QS_OFF);  // [64][136]
    float* tmp  = lds + TMP_OFF;
    float* cc   = lds + CC_OFF;
    float* mup  = lds + MUP_OFF;
    float* s2p  = lds + S2P_OFF;
    float* mu_s = lds + MU_OFF;
    float* s2_s = lds + S2_OFF;
    float* lnw  = lds + LNW_OFF;
    float* lnb  = lds + LNB_OFF;

    const int tid = threadIdx.x;
    const int px = blockIdx.x, py = blockIdx.y, bz = blockIdx.z;
    const int lane = tid & 63;
    const int wv   = tid >> 6;     // wave 0..7
    const int m16  = lane & 15;
    const int quad = lane >> 4;

    // ---- stage x tile (10x10 + halo) into xs as fp16; rows 100..111 zeroed ----
    {
        const int pix = tid & 127;
        const int gg  = tid >> 7;  // 0..3 -> 16 channels each
        const int prow = pix / 10;
        const int pcol = pix - prow * 10;
        const int yy = py * 8 + prow - 1;
        const int xx = px * 8 + pcol - 1;
        const bool inimg = (pix < 100) && ((unsigned)yy < 256u) && ((unsigned)xx < 256u);
        if (pix < 112) {
            const float* xp = inimg
                ? (x + (size_t)((bz * 64 + gg * 16) * 65536 + yy * 256 + xx)) : x;
            #pragma unroll
            for (int i = 0; i < 16; ++i) {
                const float v = inimg ? xp[(size_t)i * 65536] : 0.0f;
                xs[pix * 68 + gg * 16 + i] = (_Float16)v;
            }
        }
        if (tid < 128) { lnw[tid] = nw[tid]; lnb[tid] = nb[tid]; }
    }

    // per-phase mappings
    const int dwo = tid >> 3;          // dw / circ: channel-in-chunk 0..63
    const int blk = tid & 7;           // dw: 2x4 output block
    const int by2 = (blk >> 1) * 2;
    const int bx4 = (blk & 1) * 4;
    const int ci  = tid & 7;           // circ: output row

    f32x4 pacc2[2] = {{0.f,0.f,0.f,0.f},{0.f,0.f,0.f,0.f}};

    __syncthreads();

    #pragma unroll 1
    for (int kc = 0; kc < 6; ++kc) {
        const int o0 = kc * 64;

        // ---- 1x1 conv GEMM chunk via MFMA: hidden[o0..o0+63][pix] -> hs ----
        {
            const int ot  = wv >> 1;                 // o-tile 0..3
            const int np  = (wv & 1) ? 3 : 4;        // pix-tiles per wave
            const int pt0 = (wv & 1) * 4;
            const float* wp = wh + (size_t)(o0 + ot * 16 + m16) * 64 + quad * 8;
            const float4 w0 = *(const float4*)wp;
            const float4 w1 = *(const float4*)(wp + 4);
            const float4 w2 = *(const float4*)(wp + 32);
            const float4 w3 = *(const float4*)(wp + 36);
            const f16x8 a0 = {(_Float16)w0.x,(_Float16)w0.y,(_Float16)w0.z,(_Float16)w0.w,
                              (_Float16)w1.x,(_Float16)w1.y,(_Float16)w1.z,(_Float16)w1.w};
            const f16x8 a1 = {(_Float16)w2.x,(_Float16)w2.y,(_Float16)w2.z,(_Float16)w2.w,
                              (_Float16)w3.x,(_Float16)w3.y,(_Float16)w3.z,(_Float16)w3.w};
            for (int pp = 0; pp < np; ++pp) {
                const int pt = pt0 + pp;
                const _Float16* bp = xs + (pt * 16 + m16) * 68 + quad * 8;
                const f16x4 bl0 = *(const f16x4*)bp;
                const f16x4 bh0 = *(const f16x4*)(bp + 4);
                const f16x4 bl1 = *(const f16x4*)(bp + 32);
                const f16x4 bh1 = *(const f16x4*)(bp + 36);
                const f16x8 b0 = {bl0[0],bl0[1],bl0[2],bl0[3],bh0[0],bh0[1],bh0[2],bh0[3]};
                const f16x8 b1 = {bl1[0],bl1[1],bl1[2],bl1[3],bh1[0],bh1[1],bh1[2],bh1[3]};
                f32x4 d = {0.f,0.f,0.f,0.f};
                d = __builtin_amdgcn_mfma_f32_16x16x32_f16(a0, b0, d, 0, 0, 0);
                d = __builtin_amdgcn_mfma_f32_16x16x32_f16(a1, b1, d, 0, 0, 0);
                const int pixg = pt * 16 + m16;
                if (pixg < 100) {
                    const int oloc = ot * 16 + quad * 4;
                    #pragma unroll
                    for (int r = 0; r < 4; ++r)
                        hs[105 * (oloc + r) + pixg] = d[r];
                }
            }
        }
        __syncthreads();

        // ---- depthwise 3x3 (zero pad baked into hs halo) ----
        {
            const int og = o0 + dwo;
            float w9[9];
            #pragma unroll
            for (int t = 0; t < 9; ++t) w9[t] = wdw[og * 9 + t];
            float in[4][6];
            #pragma unroll
            for (int r = 0; r < 4; ++r)
                #pragma unroll
                for (int c = 0; c < 6; ++c)
                    in[r][c] = hs[105 * dwo + (by2 + r) * 10 + (bx4 + c)];
            float* dst = (kc < 2) ? (qs + 68 * (o0 + dwo)) : (tmp + 65 * dwo);
            #pragma unroll
            for (int r = 0; r < 2; ++r) {
                #pragma unroll
                for (int c = 0; c < 4; ++c) {
                    float s = 0.0f;
                    #pragma unroll
                    for (int dy = 0; dy < 3; ++dy)
                        #pragma unroll
                        for (int dx = 0; dx < 3; ++dx)
                            s = fmaf(w9[dy * 3 + dx], in[r + dy][c + dx], s);
                    dst[(by2 + r) * 8 + bx4 + c] = s;
                }
            }
        }
        __syncthreads();

        if (kc == 2 || kc == 3) {
            // ---- circular conv: cc[i][j] = sum_ab q[a][b]*k[(i-a)&7][(j-b)&7] ----
            const int ch = (kc - 2) * 64 + dwo;
            float q[64];
            #pragma unroll
            for (int t = 0; t < 16; ++t) {
                const float4 v4 = *(const float4*)&qs[68 * ch + 4 * t];
                q[4*t] = v4.x; q[4*t+1] = v4.y; q[4*t+2] = v4.z; q[4*t+3] = v4.w;
            }
            float acc[8];
            #pragma unroll
            for (int j = 0; j < 8; ++j) acc[j] = 0.0f;
            #pragma unroll
            for (int a = 0; a < 8; ++a) {
                const int r = (ci - a) & 7;
                float kr[8];
                #pragma unroll
                for (int j = 0; j < 8; ++j) kr[j] = tmp[65 * dwo + 8 * r + j];
                #pragma unroll
                for (int bb = 0; bb < 8; ++bb) {
                    const float qv = q[a * 8 + bb];
                    #pragma unroll
                    for (int j = 0; j < 8; ++j)
                        acc[j] = fmaf(qv, kr[(j - bb) & 7], acc[j]);
                }
            }
            #pragma unroll
            for (int j = 0; j < 8; ++j) cc[65 * ch + 8 * ci + j] = acc[j];
        }

        if (kc == 3) {
            __syncthreads();
            // ---- LN stats, all 8 waves: partials over 16 ch each ----
            const int p  = tid & 63;
            const int g8 = tid >> 6;
            float s = 0.0f, s2v = 0.0f;
            #pragma unroll
            for (int i = 0; i < 16; ++i) {
                const float v = cc[65 * (g8 * 16 + i) + p];
                s += v; s2v = fmaf(v, v, s2v);
            }
            mup[(g8 << 6) + p] = s;
            s2p[(g8 << 6) + p] = s2v;
            __syncthreads();
            if (tid < 64) {
                float t = 0.0f;
                #pragma unroll
                for (int i = 0; i < 8; ++i) t += mup[(i << 6) + tid];
                mu_s[tid] = t * (1.0f / 128.0f);
            } else if (tid < 128) {
                const int pp = tid - 64;
                float t = 0.0f;
                #pragma unroll
                for (int i = 0; i < 8; ++i) t += s2p[(i << 6) + pp];
                s2_s[pp] = t * (1.0f / 128.0f);
            }
        }

        if (kc >= 4) {
            // ---- gate: gs[pix][ch] = fp16( v * ((cc-mu)*rstd*nw + nb) ) ----
            const int p  = tid & 63;
            const int g8 = tid >> 6;
            const int cb = (kc - 4) * 64;
            const float m    = mu_s[p];
            const float rstd = rsqrtf(s2_s[p] - m * m + 1e-5f);
            f16x8 gv;
            #pragma unroll
            for (int jj = 0; jj < 8; ++jj) {
                const int chl = g8 * 8 + jj;
                const float v  = tmp[65 * chl + p];
                const float c0 = cc[65 * (cb + chl) + p];
                gv[jj] = (_Float16)(v * ((c0 - m) * rstd * lnw[cb + chl] + lnb[cb + chl]));
            }
            *(f16x8*)(gs + p * 136 + cb + g8 * 8) = gv;
            __syncthreads();
            // ---- projection MFMA: accumulate over this 64-ch chunk ----
            const int ot2 = wv >> 1;
            const float* wop = wo + (size_t)(ot2 * 16 + m16) * 128 + cb + quad * 8;
            const float4 u0 = *(const float4*)wop;
            const float4 u1 = *(const float4*)(wop + 4);
            const float4 u2 = *(const float4*)(wop + 32);
            const float4 u3 = *(const float4*)(wop + 36);
            const f16x8 pa0 = {(_Float16)u0.x,(_Float16)u0.y,(_Float16)u0.z,(_Float16)u0.w,
                               (_Float16)u1.x,(_Float16)u1.y,(_Float16)u1.z,(_Float16)u1.w};
            const f16x8 pa1 = {(_Float16)u2.x,(_Float16)u2.y,(_Float16)u2.z,(_Float16)u2.w,
                               (_Float16)u3.x,(_Float16)u3.y,(_Float16)u3.z,(_Float16)u3.w};
            #pragma unroll
            for (int tt = 0; tt < 2; ++tt) {
                const int pt = (wv & 1) * 2 + tt;
                const _Float16* bp = gs + (pt * 16 + m16) * 136 + cb + quad * 8;
                const f16x4 bl0 = *(const f16x4*)bp;
                const f16x4 bh0 = *(const f16x4*)(bp + 4);
                const f16x4 bl1 = *(const f16x4*)(bp + 32);
                const f16x4 bh1 = *(const f16x4*)(bp + 36);
                const f16x8 b0 = {bl0[0],bl0[1],bl0[2],bl0[3],bh0[0],bh0[1],bh0[2],bh0[3]};
                const f16x8 b1 = {bl1[0],bl1[1],bl1[2],bl1[3],bh1[0],bh1[1],bh1[2],bh1[3]};
                pacc2[tt] = __builtin_amdgcn_mfma_f32_16x16x32_f16(pa0, b0, pacc2[tt], 0, 0, 0);
                pacc2[tt] = __builtin_amdgcn_mfma_f32_16x16x32_f16(pa1, b1, pacc2[tt], 0, 0, 0);
            }
        }
        __syncthreads();
    }

    // ---- write output: o = ot2*16 + quad*4 + reg, pix from C-frag cols ----
    {
        const int ot2 = wv >> 1;
        #pragma unroll
        for (int tt = 0; tt < 2; ++tt) {
            const int pixg = ((wv & 1) * 2 + tt) * 16 + m16;   // 0..63
            const int r = pixg >> 3, c = pixg & 7;
            float* op = out + (size_t)(bz * 64 + ot2 * 16 + quad * 4) * 65536
                            + (py * 8 + r) * 256 + px * 8 + c;
            #pragma unroll
            for (int reg = 0; reg < 4; ++reg)
                op[(size_t)reg * 65536] = pacc2[tt][reg];
        }
    }
}

extern "C" void kernel_launch(void* const* d_in, const int* in_sizes, int n_in,
                              void* d_out, int out_size, void* d_ws, size_t ws_size,
                              hipStream_t stream) {
    const float* x   = (const float*)d_in[0];
    const float* wh  = (const float*)d_in[1];
    const float* wdw = (const float*)d_in[2];
    const float* nw  = (const float*)d_in[3];
    const float* nb  = (const float*)d_in[4];
    const float* wo  = (const float*)d_in[5];
    float* outp = (float*)d_out;

    const int lds_bytes = LDS_FLOATS * 4;  // 132480 B
    (void)hipFuncSetAttribute((const void*)lfsa_fused,
                              hipFuncAttributeMaxDynamicSharedMemorySize, lds_bytes);
    dim3 grid(32, 32, 4);
    lfsa_fused<<<grid, 512, lds_bytes, stream>>>(x, wh, wdw, nw, nb, wo, outp);
}

// Round 3
// 492.919 us; speedup vs baseline: 2.3404x; 1.0971x over previous
//
#include <hip/hip_runtime.h>

// Fused: 1x1(64->384, MFMA fp16) -> dw3x3 (fp32) -> per-8x8-patch circular
//        conv(q,k) (fp32) -> channel LN -> v*norm -> 1x1(128->64, MFMA fp16)
// One workgroup per (batch, 8x8 patch). 512 threads. LDS 78464 B -> 2 blocks/CU.

typedef _Float16 f16x8 __attribute__((ext_vector_type(8)));
typedef _Float16 f16x4 __attribute__((ext_vector_type(4)));
typedef _Float16 f16x2 __attribute__((ext_vector_type(2)));
typedef float    f32x4 __attribute__((ext_vector_type(4)));

// LDS byte offsets
#define XS_OFF    0       // f16[112][68]  x tile (10x10 + zero halo)
#define HS_OFF    15232   // f16[64][106]  hidden chunk on 10x10 tile
#define QCC_OFF   28800   // f32[128][68]  q patch; circ-conv out (cc) overwrites in place
#define TMP_OFF   63616   // f16[64][72]   k/v chunk; gated fp16 (gs) aliases
#define MUP_OFF   72832   // f32[8][64]
#define S2P_OFF   74880   // f32[8][64]
#define MU_OFF    76928   // f32[64]
#define S2_OFF    77184   // f32[64]
#define LNW_OFF   77440   // f32[128]
#define LNB_OFF   77952   // f32[128]
#define LDS_BYTES 78464

__global__ __launch_bounds__(512, 4) void lfsa_fused(
    const float* __restrict__ x,
    const float* __restrict__ wh,
    const float* __restrict__ wdw,
    const float* __restrict__ nw,
    const float* __restrict__ nb,
    const float* __restrict__ wo,
    float* __restrict__ out)
{
    extern __shared__ char lds[];
    _Float16* xs   = (_Float16*)(lds + XS_OFF);
    _Float16* hs   = (_Float16*)(lds + HS_OFF);
    float*    qcc  = (float*)(lds + QCC_OFF);
    _Float16* tmp16= (_Float16*)(lds + TMP_OFF);
    _Float16* gs16 = (_Float16*)(lds + TMP_OFF);
    float*    mup  = (float*)(lds + MUP_OFF);
    float*    s2p  = (float*)(lds + S2P_OFF);
    float*    mu_s = (float*)(lds + MU_OFF);
    float*    s2_s = (float*)(lds + S2_OFF);
    float*    lnw  = (float*)(lds + LNW_OFF);
    float*    lnb  = (float*)(lds + LNB_OFF);

    const int tid = threadIdx.x;
    const int px = blockIdx.x, py = blockIdx.y, bz = blockIdx.z;
    const int lane = tid & 63;
    const int wv   = tid >> 6;     // wave 0..7
    const int m16  = lane & 15;
    const int quad = lane >> 4;

    // ---- stage x tile (10x10 + halo) into xs as fp16; rows 100..111 zeroed ----
    {
        const int pix = tid & 127;
        const int gg  = tid >> 7;  // 0..3 -> 16 channels each
        const int prow = pix / 10;
        const int pcol = pix - prow * 10;
        const int yy = py * 8 + prow - 1;
        const int xx = px * 8 + pcol - 1;
        const bool inimg = (pix < 100) && ((unsigned)yy < 256u) && ((unsigned)xx < 256u);
        if (pix < 112) {
            const float* xp = inimg
                ? (x + (size_t)((bz * 64 + gg * 16) * 65536 + yy * 256 + xx)) : x;
            #pragma unroll
            for (int i = 0; i < 16; ++i) {
                const float v = inimg ? xp[(size_t)i * 65536] : 0.0f;
                xs[pix * 68 + gg * 16 + i] = (_Float16)v;
            }
        }
        if (tid < 128) { lnw[tid] = nw[tid]; lnb[tid] = nb[tid]; }
    }

    // per-phase mappings
    const int dwo = tid >> 3;          // dw / circ: channel-in-chunk 0..63
    const int blk = tid & 7;           // dw: 2x4 output block
    const int by2 = (blk >> 1) * 2;
    const int bx4 = (blk & 1) * 4;
    const int ci  = tid & 7;           // circ: output row

    f32x4 pacc2[2] = {{0.f,0.f,0.f,0.f},{0.f,0.f,0.f,0.f}};

    __syncthreads();

    #pragma unroll 1
    for (int kc = 0; kc < 6; ++kc) {
        const int o0 = kc * 64;

        // ---- 1x1 conv GEMM chunk via MFMA -> hs (fp16) ----
        {
            const int ot  = wv >> 1;                 // o-tile 0..3
            const int np  = (wv & 1) ? 3 : 4;        // pix-tiles per wave
            const int pt0 = (wv & 1) * 4;
            const float* wp = wh + (size_t)(o0 + ot * 16 + m16) * 64 + quad * 8;
            const float4 w0 = *(const float4*)wp;
            const float4 w1 = *(const float4*)(wp + 4);
            const float4 w2 = *(const float4*)(wp + 32);
            const float4 w3 = *(const float4*)(wp + 36);
            const f16x8 a0 = {(_Float16)w0.x,(_Float16)w0.y,(_Float16)w0.z,(_Float16)w0.w,
                              (_Float16)w1.x,(_Float16)w1.y,(_Float16)w1.z,(_Float16)w1.w};
            const f16x8 a1 = {(_Float16)w2.x,(_Float16)w2.y,(_Float16)w2.z,(_Float16)w2.w,
                              (_Float16)w3.x,(_Float16)w3.y,(_Float16)w3.z,(_Float16)w3.w};
            for (int pp = 0; pp < np; ++pp) {
                const int pt = pt0 + pp;
                const _Float16* bp = xs + (pt * 16 + m16) * 68 + quad * 8;
                const f16x4 bl0 = *(const f16x4*)bp;
                const f16x4 bh0 = *(const f16x4*)(bp + 4);
                const f16x4 bl1 = *(const f16x4*)(bp + 32);
                const f16x4 bh1 = *(const f16x4*)(bp + 36);
                const f16x8 b0 = {bl0[0],bl0[1],bl0[2],bl0[3],bh0[0],bh0[1],bh0[2],bh0[3]};
                const f16x8 b1 = {bl1[0],bl1[1],bl1[2],bl1[3],bh1[0],bh1[1],bh1[2],bh1[3]};
                f32x4 d = {0.f,0.f,0.f,0.f};
                d = __builtin_amdgcn_mfma_f32_16x16x32_f16(a0, b0, d, 0, 0, 0);
                d = __builtin_amdgcn_mfma_f32_16x16x32_f16(a1, b1, d, 0, 0, 0);
                const int pixg = pt * 16 + m16;
                if (pixg < 100) {
                    const int oloc = ot * 16 + quad * 4;
                    #pragma unroll
                    for (int r = 0; r < 4; ++r)
                        hs[106 * (oloc + r) + pixg] = (_Float16)d[r];
                }
            }
        }
        __syncthreads();

        // ---- depthwise 3x3 (zero pad baked into hs halo) ----
        {
            const int og = o0 + dwo;
            float w9[9];
            #pragma unroll
            for (int t = 0; t < 9; ++t) w9[t] = wdw[og * 9 + t];
            const _Float16* hrow = hs + 106 * dwo;
            float in[4][6];
            #pragma unroll
            for (int r = 0; r < 4; ++r) {
                const _Float16* rp = hrow + (by2 + r) * 10 + bx4;
                const f16x2 p0 = *(const f16x2*)rp;
                const f16x2 p1 = *(const f16x2*)(rp + 2);
                const f16x2 p2 = *(const f16x2*)(rp + 4);
                in[r][0] = (float)p0[0]; in[r][1] = (float)p0[1];
                in[r][2] = (float)p1[0]; in[r][3] = (float)p1[1];
                in[r][4] = (float)p2[0]; in[r][5] = (float)p2[1];
            }
            #pragma unroll
            for (int r = 0; r < 2; ++r) {
                float rv[4];
                #pragma unroll
                for (int c = 0; c < 4; ++c) {
                    float s = 0.0f;
                    #pragma unroll
                    for (int dy = 0; dy < 3; ++dy)
                        #pragma unroll
                        for (int dx = 0; dx < 3; ++dx)
                            s = fmaf(w9[dy * 3 + dx], in[r + dy][c + dx], s);
                    rv[c] = s;
                }
                const int off = (by2 + r) * 8 + bx4;
                if (kc < 2) {
                    float* qrow = qcc + 68 * (kc * 64 + dwo);
                    *(f32x4*)(qrow + off) = {rv[0], rv[1], rv[2], rv[3]};
                } else {
                    _Float16* trow = tmp16 + 72 * dwo;
                    const f16x4 hv = {(_Float16)rv[0], (_Float16)rv[1],
                                      (_Float16)rv[2], (_Float16)rv[3]};
                    *(f16x4*)(trow + off) = hv;
                }
            }
        }
        __syncthreads();

        if (kc == 2 || kc == 3) {
            // ---- circular conv: cc[i][j] = sum_ab q[a][b]*k[(i-a)&7][(j-b)&7] ----
            // q row is fully consumed into regs before cc overwrites it (same rows,
            // readers of a q row are the 8 lanes sharing dwo -> same wave, lockstep).
            const int ch = (kc - 2) * 64 + dwo;
            float* qrow = qcc + 68 * ch;
            float q[64];
            #pragma unroll
            for (int t = 0; t < 16; ++t) {
                const f32x4 v4 = *(const f32x4*)(qrow + 4 * t);
                q[4*t] = v4[0]; q[4*t+1] = v4[1]; q[4*t+2] = v4[2]; q[4*t+3] = v4[3];
            }
            float acc[8];
            #pragma unroll
            for (int j = 0; j < 8; ++j) acc[j] = 0.0f;
            #pragma unroll
            for (int a = 0; a < 8; ++a) {
                const int r = (ci - a) & 7;
                const f16x8 krh = *(const f16x8*)(tmp16 + 72 * dwo + 8 * r);
                float kr[8];
                #pragma unroll
                for (int j = 0; j < 8; ++j) kr[j] = (float)krh[j];
                #pragma unroll
                for (int bb = 0; bb < 8; ++bb) {
                    const float qv = q[a * 8 + bb];
                    #pragma unroll
                    for (int j = 0; j < 8; ++j)
                        acc[j] = fmaf(qv, kr[(j - bb) & 7], acc[j]);
                }
            }
            *(f32x4*)(qrow + 8 * ci)     = {acc[0], acc[1], acc[2], acc[3]};
            *(f32x4*)(qrow + 8 * ci + 4) = {acc[4], acc[5], acc[6], acc[7]};
        }

        if (kc == 3) {
            __syncthreads();
            // ---- LN stats, all 8 waves: partials over 16 ch each ----
            const int p  = tid & 63;
            const int g8 = tid >> 6;
            float s = 0.0f, s2v = 0.0f;
            #pragma unroll
            for (int i = 0; i < 16; ++i) {
                const float v = qcc[68 * (g8 * 16 + i) + p];
                s += v; s2v = fmaf(v, v, s2v);
            }
            mup[(g8 << 6) + p] = s;
            s2p[(g8 << 6) + p] = s2v;
            __syncthreads();
            if (tid < 64) {
                float t = 0.0f;
                #pragma unroll
                for (int i = 0; i < 8; ++i) t += mup[(i << 6) + tid];
                mu_s[tid] = t * (1.0f / 128.0f);
            } else if (tid < 128) {
                const int pp = tid - 64;
                float t = 0.0f;
                #pragma unroll
                for (int i = 0; i < 8; ++i) t += s2p[(i << 6) + pp];
                s2_s[pp] = t * (1.0f / 128.0f);
            }
        }

        if (kc >= 4) {
            // ---- gate: read v (tmp16) + cc, then overwrite tmp16 with gs fp16 ----
            const int p  = tid & 63;
            const int g8 = tid >> 6;
            const int cb = (kc - 4) * 64;
            const float m    = mu_s[p];
            const float rstd = rsqrtf(s2_s[p] - m * m + 1e-5f);
            float vv[8], c0[8];
            #pragma unroll
            for (int jj = 0; jj < 8; ++jj) {
                const int chl = g8 * 8 + jj;
                vv[jj] = (float)tmp16[72 * chl + p];
                c0[jj] = qcc[68 * (cb + chl) + p];
            }
            __syncthreads();
            f16x8 gv;
            #pragma unroll
            for (int jj = 0; jj < 8; ++jj) {
                const int chl = g8 * 8 + jj;
                gv[jj] = (_Float16)(vv[jj] * ((c0[jj] - m) * rstd * lnw[cb + chl]
                                              + lnb[cb + chl]));
            }
            *(f16x8*)(gs16 + p * 72 + g8 * 8) = gv;
            __syncthreads();
            // ---- projection MFMA over this 64-ch chunk ----
            const int ot2 = wv >> 1;
            const float* wop = wo + (size_t)(ot2 * 16 + m16) * 128 + cb + quad * 8;
            const float4 u0 = *(const float4*)wop;
            const float4 u1 = *(const float4*)(wop + 4);
            const float4 u2 = *(const float4*)(wop + 32);
            const float4 u3 = *(const float4*)(wop + 36);
            const f16x8 pa0 = {(_Float16)u0.x,(_Float16)u0.y,(_Float16)u0.z,(_Float16)u0.w,
                               (_Float16)u1.x,(_Float16)u1.y,(_Float16)u1.z,(_Float16)u1.w};
            const f16x8 pa1 = {(_Float16)u2.x,(_Float16)u2.y,(_Float16)u2.z,(_Float16)u2.w,
                               (_Float16)u3.x,(_Float16)u3.y,(_Float16)u3.z,(_Float16)u3.w};
            #pragma unroll
            for (int tt = 0; tt < 2; ++tt) {
                const int pt = (wv & 1) * 2 + tt;
                const _Float16* bp = gs16 + (pt * 16 + m16) * 72 + quad * 8;
                const f16x8 b0 = *(const f16x8*)bp;
                const f16x8 b1 = *(const f16x8*)(bp + 32);
                pacc2[tt] = __builtin_amdgcn_mfma_f32_16x16x32_f16(pa0, b0, pacc2[tt], 0, 0, 0);
                pacc2[tt] = __builtin_amdgcn_mfma_f32_16x16x32_f16(pa1, b1, pacc2[tt], 0, 0, 0);
            }
        }
        __syncthreads();
    }

    // ---- write output: o = ot2*16 + quad*4 + reg, pix from C-frag cols ----
    {
        const int ot2 = wv >> 1;
        #pragma unroll
        for (int tt = 0; tt < 2; ++tt) {
            const int pixg = ((wv & 1) * 2 + tt) * 16 + m16;   // 0..63
            const int r = pixg >> 3, c = pixg & 7;
            float* op = out + (size_t)(bz * 64 + ot2 * 16 + quad * 4) * 65536
                            + (py * 8 + r) * 256 + px * 8 + c;
            #pragma unroll
            for (int reg = 0; reg < 4; ++reg)
                op[(size_t)reg * 65536] = pacc2[tt][reg];
        }
    }
}

extern "C" void kernel_launch(void* const* d_in, const int* in_sizes, int n_in,
                              void* d_out, int out_size, void* d_ws, size_t ws_size,
                              hipStream_t stream) {
    const float* x   = (const float*)d_in[0];
    const float* wh  = (const float*)d_in[1];
    const float* wdw = (const float*)d_in[2];
    const float* nw  = (const float*)d_in[3];
    const float* nb  = (const float*)d_in[4];
    const float* wo  = (const float*)d_in[5];
    float* outp = (float*)d_out;

    (void)hipFuncSetAttribute((const void*)lfsa_fused,
                              hipFuncAttributeMaxDynamicSharedMemorySize, LDS_BYTES);
    dim3 grid(32, 32, 4);
    lfsa_fused<<<grid, 512, LDS_BYTES, stream>>>(x, wh, wdw, nw, nb, wo, outp);
}

// Round 5
// 412.319 us; speedup vs baseline: 2.7979x; 1.1955x over previous
//
#include <hip/hip_runtime.h>

// Fused: 1x1(64->384, MFMA fp16) -> dw3x3 (fp32) -> per-8x8-patch circular
//        conv(q,k) (fdot2 fp16-pairs, fp32 acc) -> channel LN (shfl reduce)
//        -> v*norm (in-place gate) -> 1x1(128->64, MFMA fp16)
// One workgroup per (batch, 8x8 patch). 512 threads. LDS 74368 B -> 2 blocks/CU.
// Barrier schedule: 2/kc + 1 (kc3 LN) + 2 (kc4,5 gate->proj) = 15 total.

typedef _Float16 f16x8 __attribute__((ext_vector_type(8)));
typedef _Float16 f16x4 __attribute__((ext_vector_type(4)));
typedef _Float16 f16x2 __attribute__((ext_vector_type(2)));
typedef __fp16   h16x2 __attribute__((ext_vector_type(2)));   // builtin ABI type
typedef float    f32x4 __attribute__((ext_vector_type(4)));

// LDS byte offsets
#define XS_OFF    0       // f16[112][68]  x tile (10x10 + zero halo)
#define HS_OFF    15232   // f16[64][106]  hidden chunk on 10x10 tile
#define QCC_OFF   28800   // f32[128][68]  q patch; cc overwrites in place
#define TMP_OFF   63616   // f16[64][72]   k chunk [ch][pix]; gs[pix][ch] aliases kc>=4
#define MU_OFF    72832   // f32[64]
#define S2_OFF    73088   // f32[64]
#define LNW_OFF   73344   // f32[128]
#define LNB_OFF   73856   // f32[128]
#define LDS_BYTES 74368

__global__ __launch_bounds__(512, 4) void lfsa_fused(
    const float* __restrict__ x,
    const float* __restrict__ wh,
    const float* __restrict__ wdw,
    const float* __restrict__ nw,
    const float* __restrict__ nb,
    const float* __restrict__ wo,
    float* __restrict__ out)
{
    extern __shared__ char lds[];
    _Float16* xs    = (_Float16*)(lds + XS_OFF);
    _Float16* hs    = (_Float16*)(lds + HS_OFF);
    float*    qcc   = (float*)(lds + QCC_OFF);
    _Float16* tmp16 = (_Float16*)(lds + TMP_OFF);   // k chunks [ch][72]
    _Float16* gs16  = (_Float16*)(lds + TMP_OFF);   // gated v  [pix][72]
    float*    mu_s  = (float*)(lds + MU_OFF);
    float*    s2_s  = (float*)(lds + S2_OFF);
    float*    lnw   = (float*)(lds + LNW_OFF);
    float*    lnb   = (float*)(lds + LNB_OFF);

    const int tid = threadIdx.x;
    const int px = blockIdx.x, py = blockIdx.y, bz = blockIdx.z;
    const int lane = tid & 63;
    const int wv   = tid >> 6;     // wave 0..7
    const int m16  = lane & 15;
    const int quad = lane >> 4;

    // ---- stage x tile (10x10 + halo) into xs as fp16; rows 100..111 zeroed ----
    {
        const int pix = tid & 127;
        const int gg  = tid >> 7;  // 0..3 -> 16 channels each
        const int prow = pix / 10;
        const int pcol = pix - prow * 10;
        const int yy = py * 8 + prow - 1;
        const int xx = px * 8 + pcol - 1;
        const bool inimg = (pix < 100) && ((unsigned)yy < 256u) && ((unsigned)xx < 256u);
        if (pix < 112) {
            const float* xp = inimg
                ? (x + (size_t)((bz * 64 + gg * 16) * 65536 + yy * 256 + xx)) : x;
            #pragma unroll
            for (int i = 0; i < 16; ++i) {
                const float v = inimg ? xp[(size_t)i * 65536] : 0.0f;
                xs[pix * 68 + gg * 16 + i] = (_Float16)v;
            }
        }
        if (tid < 128) { lnw[tid] = nw[tid]; lnb[tid] = nb[tid]; }
    }

    // per-phase mappings
    const int dwo = tid >> 3;          // dw / circ: channel-in-chunk 0..63
    const int blk = tid & 7;           // dw: block (row-strip kc<4, col-strip kc>=4)
    const int by2 = (blk >> 1) * 2;
    const int bx4 = (blk & 1) * 4;
    const int ci  = tid & 7;           // circ: output row

    // ---- weight prefetch registers ----
    const int ot = wv >> 1;            // GEMM1 o-tile 0..3
    const float* wha = wh + (size_t)(ot * 16 + m16) * 64 + quad * 8;
    float4 wr0 = *(const float4*)(wha);
    float4 wr1 = *(const float4*)(wha + 4);
    float4 wr2 = *(const float4*)(wha + 32);
    float4 wr3 = *(const float4*)(wha + 36);
    float w9n[9];
    #pragma unroll
    for (int t = 0; t < 9; ++t) w9n[t] = wdw[dwo * 9 + t];
    float4 wo0, wo1, wo2, wo3;         // wo frags, loaded at kc==3 / kc==4

    f32x4 pacc2[2] = {{0.f,0.f,0.f,0.f},{0.f,0.f,0.f,0.f}};

    __syncthreads();

    #pragma unroll 1
    for (int kc = 0; kc < 6; ++kc) {
        // ---- materialize current weights, issue next-kc prefetch ----
        const f16x8 a0 = {(_Float16)wr0.x,(_Float16)wr0.y,(_Float16)wr0.z,(_Float16)wr0.w,
                          (_Float16)wr1.x,(_Float16)wr1.y,(_Float16)wr1.z,(_Float16)wr1.w};
        const f16x8 a1 = {(_Float16)wr2.x,(_Float16)wr2.y,(_Float16)wr2.z,(_Float16)wr2.w,
                          (_Float16)wr3.x,(_Float16)wr3.y,(_Float16)wr3.z,(_Float16)wr3.w};
        float w9c[9];
        #pragma unroll
        for (int t = 0; t < 9; ++t) w9c[t] = w9n[t];
        if (kc < 5) {
            const float* nx = wha + (size_t)(kc + 1) * 4096;
            wr0 = *(const float4*)(nx);
            wr1 = *(const float4*)(nx + 4);
            wr2 = *(const float4*)(nx + 32);
            wr3 = *(const float4*)(nx + 36);
            #pragma unroll
            for (int t = 0; t < 9; ++t) w9n[t] = wdw[(kc + 1) * 576 + dwo * 9 + t];
        }
        if (kc == 3) {
            const float* wop = wo + (size_t)(ot * 16 + m16) * 128 + quad * 8;
            wo0 = *(const float4*)(wop);
            wo1 = *(const float4*)(wop + 4);
            wo2 = *(const float4*)(wop + 32);
            wo3 = *(const float4*)(wop + 36);
        }

        // ---- 1x1 conv GEMM chunk via MFMA -> hs (fp16) ----
        {
            const int np  = (wv & 1) ? 3 : 4;
            const int pt0 = (wv & 1) * 4;
            for (int pp = 0; pp < np; ++pp) {
                const int pt = pt0 + pp;
                const _Float16* bp = xs + (pt * 16 + m16) * 68 + quad * 8;
                const f16x4 bl0 = *(const f16x4*)bp;
                const f16x4 bh0 = *(const f16x4*)(bp + 4);
                const f16x4 bl1 = *(const f16x4*)(bp + 32);
                const f16x4 bh1 = *(const f16x4*)(bp + 36);
                const f16x8 b0 = {bl0[0],bl0[1],bl0[2],bl0[3],bh0[0],bh0[1],bh0[2],bh0[3]};
                const f16x8 b1 = {bl1[0],bl1[1],bl1[2],bl1[3],bh1[0],bh1[1],bh1[2],bh1[3]};
                f32x4 d = {0.f,0.f,0.f,0.f};
                d = __builtin_amdgcn_mfma_f32_16x16x32_f16(a0, b0, d, 0, 0, 0);
                d = __builtin_amdgcn_mfma_f32_16x16x32_f16(a1, b1, d, 0, 0, 0);
                const int pixg = pt * 16 + m16;
                if (pixg < 100) {
                    const int oloc = ot * 16 + quad * 4;
                    #pragma unroll
                    for (int r = 0; r < 4; ++r)
                        hs[106 * (oloc + r) + pixg] = (_Float16)d[r];
                }
            }
        }
        __syncthreads();   // (1) hs ready; also fences prior-kc consumer reads

        // ---- depthwise 3x3 ----
        if (kc < 4) {
            // row-strip 2x4 block -> q (fp32) or k (fp16 [ch][pix])
            const _Float16* hrow = hs + 106 * dwo;
            float in[4][6];
            #pragma unroll
            for (int r = 0; r < 4; ++r) {
                const _Float16* rp = hrow + (by2 + r) * 10 + bx4;
                const f16x2 p0 = *(const f16x2*)rp;
                const f16x2 p1 = *(const f16x2*)(rp + 2);
                const f16x2 p2 = *(const f16x2*)(rp + 4);
                in[r][0] = (float)p0[0]; in[r][1] = (float)p0[1];
                in[r][2] = (float)p1[0]; in[r][3] = (float)p1[1];
                in[r][4] = (float)p2[0]; in[r][5] = (float)p2[1];
            }
            #pragma unroll
            for (int r = 0; r < 2; ++r) {
                float rv[4];
                #pragma unroll
                for (int c = 0; c < 4; ++c) {
                    float s = 0.0f;
                    #pragma unroll
                    for (int dy = 0; dy < 3; ++dy)
                        #pragma unroll
                        for (int dx = 0; dx < 3; ++dx)
                            s = fmaf(w9c[dy * 3 + dx], in[r + dy][c + dx], s);
                    rv[c] = s;
                }
                const int off = (by2 + r) * 8 + bx4;
                if (kc < 2) {
                    float* qrow = qcc + 68 * (kc * 64 + dwo);
                    *(f32x4*)(qrow + off) = {rv[0], rv[1], rv[2], rv[3]};
                } else {
                    _Float16* trow = tmp16 + 72 * dwo;
                    *(f16x4*)(trow + off) = f16x4{(_Float16)rv[0], (_Float16)rv[1],
                                                  (_Float16)rv[2], (_Float16)rv[3]};
                }
            }
        } else {
            // col-strip: 8 rows of column blk -> gs[pix][ch] (conflict-free writes)
            const _Float16* hrow = hs + 106 * dwo;
            float c0[10], c1[10], c2[10];
            #pragma unroll
            for (int rr = 0; rr < 10; ++rr) {
                c0[rr] = (float)hrow[rr * 10 + blk];
                c1[rr] = (float)hrow[rr * 10 + blk + 1];
                c2[rr] = (float)hrow[rr * 10 + blk + 2];
            }
            #pragma unroll
            for (int r = 0; r < 8; ++r) {
                float s = 0.0f;
                #pragma unroll
                for (int dy = 0; dy < 3; ++dy) {
                    s = fmaf(w9c[dy * 3 + 0], c0[r + dy], s);
                    s = fmaf(w9c[dy * 3 + 1], c1[r + dy], s);
                    s = fmaf(w9c[dy * 3 + 2], c2[r + dy], s);
                }
                gs16[(r * 8 + blk) * 72 + dwo] = (_Float16)s;
            }
        }
        __syncthreads();   // (2) dw output ready; fences hs reads vs next GEMM

        if (kc == 2 || kc == 3) {
            // ---- circular conv via fdot2: cc[i][j] = sum q[a][b] k[(i-a)][(j-b)] ----
            const int ch = (kc - 2) * 64 + dwo;
            float* qrow = qcc + 68 * ch;
            const _Float16* krow = tmp16 + 72 * dwo;
            float acc[8];
            #pragma unroll
            for (int j = 0; j < 8; ++j) acc[j] = 0.0f;
            #pragma unroll
            for (int a = 0; a < 8; ++a) {
                const f32x4 qa = *(const f32x4*)(qrow + 8 * a);
                const f32x4 qb = *(const f32x4*)(qrow + 8 * a + 4);
                h16x2 q2[4];
                q2[0] = __builtin_amdgcn_cvt_pkrtz(qa[0], qa[1]);
                q2[1] = __builtin_amdgcn_cvt_pkrtz(qa[2], qa[3]);
                q2[2] = __builtin_amdgcn_cvt_pkrtz(qb[0], qb[1]);
                q2[3] = __builtin_amdgcn_cvt_pkrtz(qb[2], qb[3]);
                const int r = (ci - a) & 7;
                const f16x8 kr = *(const f16x8*)(krow + 8 * r);
                h16x2 rp[8];
                #pragma unroll
                for (int i = 0; i < 8; ++i)
                    rp[i] = h16x2{(__fp16)kr[i], (__fp16)kr[(i + 7) & 7]};
                #pragma unroll
                for (int j = 0; j < 8; ++j)
                    #pragma unroll
                    for (int t = 0; t < 4; ++t)
                        acc[j] = __builtin_amdgcn_fdot2(q2[t], rp[(j - 2 * t) & 7],
                                                        acc[j], false);
            }
            // all q reads of this wave precede these stores (lockstep) -> safe
            *(f32x4*)(qrow + 8 * ci)     = {acc[0], acc[1], acc[2], acc[3]};
            *(f32x4*)(qrow + 8 * ci + 4) = {acc[4], acc[5], acc[6], acc[7]};
        }

        if (kc == 3) {
            __syncthreads();   // (3) cc complete before LN reads
            // ---- LN stats: wave w covers pixels 8w..8w+7; shfl-xor reduce ----
            const int p = 8 * wv + (lane & 7);
            const int g = lane >> 3;
            float s = 0.0f, s2v = 0.0f;
            #pragma unroll
            for (int i = 0; i < 16; ++i) {
                const float v = qcc[68 * (g + 8 * i) + p];
                s += v; s2v = fmaf(v, v, s2v);
            }
            #pragma unroll
            for (int m = 8; m < 64; m <<= 1) {
                s   += __shfl_xor(s, m, 64);
                s2v += __shfl_xor(s2v, m, 64);
            }
            if (lane < 8) {
                mu_s[p] = s * (1.0f / 128.0f);
                s2_s[p] = s2v * (1.0f / 128.0f);
            }
        }

        if (kc >= 4) {
            // ---- gate in place: gs[p][ch] *= LN(cc)  (same-thread RMW, no sync) ----
            const int p  = tid & 63;
            const int g8 = wv;
            const int cb = (kc - 4) * 64;
            const float m    = mu_s[p];
            const float rstd = rsqrtf(s2_s[p] - m * m + 1e-5f);
            const f16x8 vv = *(const f16x8*)(gs16 + p * 72 + g8 * 8);
            f16x8 gv;
            #pragma unroll
            for (int jj = 0; jj < 8; ++jj) {
                const int chl = g8 * 8 + jj;
                const float c0 = qcc[68 * (cb + chl) + p];
                gv[jj] = (_Float16)((float)vv[jj] *
                         ((c0 - m) * rstd * lnw[cb + chl] + lnb[cb + chl]));
            }
            *(f16x8*)(gs16 + p * 72 + g8 * 8) = gv;
            __syncthreads();   // (4) gated values ready for proj
            // ---- projection MFMA over this 64-ch chunk ----
            const f16x8 pa0 = {(_Float16)wo0.x,(_Float16)wo0.y,(_Float16)wo0.z,(_Float16)wo0.w,
                               (_Float16)wo1.x,(_Float16)wo1.y,(_Float16)wo1.z,(_Float16)wo1.w};
            const f16x8 pa1 = {(_Float16)wo2.x,(_Float16)wo2.y,(_Float16)wo2.z,(_Float16)wo2.w,
                               (_Float16)wo3.x,(_Float16)wo3.y,(_Float16)wo3.z,(_Float16)wo3.w};
            #pragma unroll
            for (int tt = 0; tt < 2; ++tt) {
                const int pt = (wv & 1) * 2 + tt;
                const _Float16* bp = gs16 + (pt * 16 + m16) * 72 + quad * 8;
                const f16x8 b0 = *(const f16x8*)bp;
                const f16x8 b1 = *(const f16x8*)(bp + 32);
                pacc2[tt] = __builtin_amdgcn_mfma_f32_16x16x32_f16(pa0, b0, pacc2[tt], 0, 0, 0);
                pacc2[tt] = __builtin_amdgcn_mfma_f32_16x16x32_f16(pa1, b1, pacc2[tt], 0, 0, 0);
            }
            if (kc == 4) {   // prefetch wo frags for cb=64
                const float* wop = wo + (size_t)(ot * 16 + m16) * 128 + 64 + quad * 8;
                wo0 = *(const float4*)(wop);
                wo1 = *(const float4*)(wop + 4);
                wo2 = *(const float4*)(wop + 32);
                wo3 = *(const float4*)(wop + 36);
            }
        }
    }

    // ---- write output: o = ot*16 + quad*4 + reg, pix from C-frag cols ----
    {
        #pragma unroll
        for (int tt = 0; tt < 2; ++tt) {
            const int pixg = ((wv & 1) * 2 + tt) * 16 + m16;   // 0..63
            const int r = pixg >> 3, c = pixg & 7;
            float* op = out + (size_t)(bz * 64 + ot * 16 + quad * 4) * 65536
                            + (py * 8 + r) * 256 + px * 8 + c;
            #pragma unroll
            for (int reg = 0; reg < 4; ++reg)
                op[(size_t)reg * 65536] = pacc2[tt][reg];
        }
    }
}

extern "C" void kernel_launch(void* const* d_in, const int* in_sizes, int n_in,
                              void* d_out, int out_size, void* d_ws, size_t ws_size,
                              hipStream_t stream) {
    const float* x   = (const float*)d_in[0];
    const float* wh  = (const float*)d_in[1];
    const float* wdw = (const float*)d_in[2];
    const float* nw  = (const float*)d_in[3];
    const float* nb  = (const float*)d_in[4];
    const float* wo  = (const float*)d_in[5];
    float* outp = (float*)d_out;

    (void)hipFuncSetAttribute((const void*)lfsa_fused,
                              hipFuncAttributeMaxDynamicSharedMemorySize, LDS_BYTES);
    dim3 grid(32, 32, 4);
    lfsa_fused<<<grid, 512, LDS_BYTES, stream>>>(x, wh, wdw, nw, nb, wo, outp);
}